// Round 5
// baseline (569.481 us; speedup 1.0000x reference)
//
#include <hip/hip_runtime.h>
#include <hip/hip_bf16.h>
#include <cmath>

#define N_NODES 50000
#define N_EDGES 800000
#define HID 64
#define HEADS 4
#define CONVS 2
#define CLS 16
#define SLOPE 0.2f
#define SCAN_B 1024
#define LOG2E 1.4426950408889634f
#define CAP 192

typedef unsigned int  uint32;
typedef unsigned short ushort16;

__device__ __forceinline__ ushort16 f2bf(float x) {
    union { float f; uint32 u; } v; v.f = x;
    uint32 r = v.u + 0x7fffu + ((v.u >> 16) & 1u);   // RNE
    return (ushort16)(r >> 16);
}
__device__ __forceinline__ float bf_lo(uint32 w) { return __uint_as_float(w << 16); }
__device__ __forceinline__ float bf_hi(uint32 w) { return __uint_as_float(w & 0xffff0000u); }

// ---------------- CSR build ----------------

__global__ void hist_kernel(const int* __restrict__ dst, int* __restrict__ deg) {
    int e = blockIdx.x * blockDim.x + threadIdx.x;
    if (e < N_EDGES) atomicAdd(&deg[dst[e]], 1);
}

__global__ void scan1_kernel(const int* __restrict__ deg, int* __restrict__ row_ptr,
                             int* __restrict__ tops) {
    __shared__ int buf[SCAN_B];
    int i = blockIdx.x * SCAN_B + threadIdx.x;
    int v = (i < N_NODES) ? deg[i] : 0;
    buf[threadIdx.x] = v;
    __syncthreads();
    for (int off = 1; off < SCAN_B; off <<= 1) {
        int t = (threadIdx.x >= off) ? buf[threadIdx.x - off] : 0;
        __syncthreads();
        buf[threadIdx.x] += t;
        __syncthreads();
    }
    if (i < N_NODES) row_ptr[i + 1] = buf[threadIdx.x];
    if (threadIdx.x == SCAN_B - 1) tops[blockIdx.x] = buf[threadIdx.x];
}

__global__ void scan2_kernel(int* __restrict__ tops, int nb) {
    if (threadIdx.x == 0 && blockIdx.x == 0) {
        int acc = 0;
        for (int b = 0; b < nb; b++) { int t = tops[b]; tops[b] = acc; acc += t; }
    }
}

__global__ void scan3_kernel(int* __restrict__ row_ptr, const int* __restrict__ tops) {
    int i = blockIdx.x * SCAN_B + threadIdx.x;
    if (i < N_NODES) row_ptr[i + 1] += tops[blockIdx.x];
    if (i == 0 && blockIdx.x == 0) row_ptr[0] = 0;
}

__global__ void scatter_kernel(const int* __restrict__ src, const int* __restrict__ dst,
                               const int* __restrict__ row_ptr, int* __restrict__ cursor,
                               int* __restrict__ col) {
    int e = blockIdx.x * blockDim.x + threadIdx.x;
    if (e < N_EDGES) {
        int d = dst[e];
        int pos = row_ptr[d] + atomicAdd(&cursor[d], 1);
        col[pos] = src[e];
    }
}

// ---------------- per-type projection: h = feat @ W1 + b1 (+ bf16 copy, rowsum) --------

__global__ __launch_bounds__(256)
void proj_kernel(const float* __restrict__ feat, const float* __restrict__ W,
                 const float* __restrict__ b, float* __restrict__ h,
                 ushort16* __restrict__ hb, float* __restrict__ s_out,
                 int rows, int K, int base_row) {
    int lane = threadIdx.x & 63;
    int wid  = threadIdx.x >> 6;
    int r = blockIdx.x * 4 + wid;
    if (r >= rows) return;
    const float* arow = feat + (size_t)r * K;
    float acc = b[lane];
    for (int kk = 0; kk < K; kk += 4) {
        float4 a4 = *reinterpret_cast<const float4*>(arow + kk);
        acc = fmaf(a4.x, W[(kk + 0) * 64 + lane], acc);
        acc = fmaf(a4.y, W[(kk + 1) * 64 + lane], acc);
        acc = fmaf(a4.z, W[(kk + 2) * 64 + lane], acc);
        acc = fmaf(a4.w, W[(kk + 3) * 64 + lane], acc);
    }
    int gr = base_row + r;
    h[(size_t)gr * 64 + lane]  = acc;
    hb[(size_t)gr * 64 + lane] = f2bf(acc);
    float ssum = acc;
    #pragma unroll
    for (int off = 32; off; off >>= 1) ssum += __shfl_xor(ssum, off);
    if (lane == 0) s_out[gr] = ssum;
}

// ------- conv 0: LDS-staged (col_off, s) + 4-deep x prefetch; 4 heads fused -------

__global__ __launch_bounds__(256)
void conv0_kernel(const ushort16* __restrict__ hb, const float* __restrict__ s_h,
                  const float* __restrict__ al, const float* __restrict__ ar,
                  const int* __restrict__ row_ptr, const int* __restrict__ col,
                  ushort16* __restrict__ x1p, float4* __restrict__ s1p) {
    __shared__ uint2 sh_cs[4][CAP + 4];
    int lane = threadIdx.x & 63;
    int wid  = threadIdx.x >> 6;
    int n = blockIdx.x * 4 + wid;
    if (n >= N_NODES) return;

    float sd = s_h[n];
    int base = row_ptr[n];
    int deg  = row_ptr[n + 1] - base;

    float alk[HEADS], ck[HEADS], alkB[HEADS], ckA[HEADS], ckB[HEADS], den[HEADS], num[HEADS];
    #pragma unroll
    for (int hd = 0; hd < HEADS; hd++) {
        alk[hd] = al[(hd * CONVS + 0) * 64 + lane] * LOG2E;
        ck[hd]  = ar[(hd * CONVS + 0) * 64 + lane] * LOG2E * sd;
    }

    float smax = -INFINITY, smin = INFINITY;
    auto finalize = [&]() {
        #pragma unroll
        for (int off = 32; off; off >>= 1) {
            smax = fmaxf(smax, __shfl_xor(smax, off));
            smin = fminf(smin, __shfl_xor(smin, off));
        }
        #pragma unroll
        for (int hd = 0; hd < HEADS; hd++) {
            float t1 = fmaf(alk[hd], smax, ck[hd]); t1 = fmaxf(t1, SLOPE * t1);
            float t2 = fmaf(alk[hd], smin, ck[hd]); t2 = fmaxf(t2, SLOPE * t2);
            float mm = fmaxf(t1, t2);
            alkB[hd] = SLOPE * alk[hd];
            ckA[hd]  = ck[hd] - mm;
            ckB[hd]  = SLOPE * ck[hd] - mm;
            den[hd] = 0.f; num[hd] = 0.f;
        }
    };

    bool big = deg > CAP;
    if (big) {
        for (int j = lane; j < deg; j += 64) {
            float sv = s_h[col[base + j]];
            smax = fmaxf(smax, sv);
            smin = fminf(smin, sv);
        }
        finalize();
    }

#define C0C(SV, HV)                                                                \
    {                                                                              \
        float hf = __uint_as_float((HV) << 16);                                    \
        float w0 = exp2f(fmaxf(fmaf(alk[0], (SV), ckA[0]), fmaf(alkB[0], (SV), ckB[0]))); \
        float w1 = exp2f(fmaxf(fmaf(alk[1], (SV), ckA[1]), fmaf(alkB[1], (SV), ckB[1]))); \
        float w2 = exp2f(fmaxf(fmaf(alk[2], (SV), ckA[2]), fmaf(alkB[2], (SV), ckB[2]))); \
        float w3 = exp2f(fmaxf(fmaf(alk[3], (SV), ckA[3]), fmaf(alkB[3], (SV), ckB[3]))); \
        den[0] += w0; den[1] += w1; den[2] += w2; den[3] += w3;                    \
        num[0] = fmaf(hf, w0, num[0]); num[1] = fmaf(hf, w1, num[1]);              \
        num[2] = fmaf(hf, w2, num[2]); num[3] = fmaf(hf, w3, num[3]);              \
    }

    uint2* csw = sh_cs[wid];
    const char* xb = (const char*)hb + (size_t)lane * 2;   // 2B/lane, row = 128B
    int done = 0;
    while (done < deg) {
        int CH = min(deg - done, CAP);
        for (int j = lane; j < CH; j += 64) {
            int c = col[base + done + j];
            float sv = s_h[c];
            csw[j] = make_uint2((uint32)c << 7, __float_as_uint(sv));
            if (!big) { smax = fmaxf(smax, sv); smin = fminf(smin, sv); }
        }
        uint2 p0 = csw[0];
        if (lane < 4) csw[CH + lane] = p0;
        if (!big) finalize();

        float s0, s1v, s2, s3;
        uint32 x0, x1v, x2, x3;
        { uint2 e = csw[0]; s0  = __uint_as_float(e.y); x0  = *(const ushort16*)(xb + e.x); }
        { uint2 e = csw[1]; s1v = __uint_as_float(e.y); x1v = *(const ushort16*)(xb + e.x); }
        { uint2 e = csw[2]; s2  = __uint_as_float(e.y); x2  = *(const ushort16*)(xb + e.x); }
        { uint2 e = csw[3]; s3  = __uint_as_float(e.y); x3  = *(const ushort16*)(xb + e.x); }

        int ch4 = CH & ~3;
        for (int j = 0; j < ch4; j += 4) {
            C0C(s0, x0);  { uint2 e = csw[j+4]; s0  = __uint_as_float(e.y); x0  = *(const ushort16*)(xb + e.x); }
            C0C(s1v, x1v);{ uint2 e = csw[j+5]; s1v = __uint_as_float(e.y); x1v = *(const ushort16*)(xb + e.x); }
            C0C(s2, x2);  { uint2 e = csw[j+6]; s2  = __uint_as_float(e.y); x2  = *(const ushort16*)(xb + e.x); }
            C0C(s3, x3);  { uint2 e = csw[j+7]; s3  = __uint_as_float(e.y); x3  = *(const ushort16*)(xb + e.x); }
        }
        int rem = CH - ch4;
        if (rem > 0) C0C(s0, x0);
        if (rem > 1) C0C(s1v, x1v);
        if (rem > 2) C0C(s2, x2);
        done += CH;
    }
#undef C0C

    float o[HEADS];
    #pragma unroll
    for (int hd = 0; hd < HEADS; hd++) o[hd] = num[hd] / den[hd];

    uint32 lo = ((uint32)f2bf(o[0])) | (((uint32)f2bf(o[1])) << 16);
    uint32 hi = ((uint32)f2bf(o[2])) | (((uint32)f2bf(o[3])) << 16);
    *reinterpret_cast<uint2*>(x1p + ((size_t)n * 64 + lane) * 4) = make_uint2(lo, hi);

    float r0 = o[0], r1 = o[1], r2 = o[2], r3 = o[3];
    #pragma unroll
    for (int off = 32; off; off >>= 1) {
        r0 += __shfl_xor(r0, off); r1 += __shfl_xor(r1, off);
        r2 += __shfl_xor(r2, off); r3 += __shfl_xor(r3, off);
    }
    if (lane == 0) s1p[n] = make_float4(r0, r1, r2, r3);
}

// ------- conv 1 + epilogue: LDS-staged (col_off, s4) + 4-deep x prefetch -------

__global__ __launch_bounds__(256)
void conv1_fused_kernel(const float* __restrict__ h, const ushort16* __restrict__ x1p,
                        const float4* __restrict__ s1p,
                        const float* __restrict__ al, const float* __restrict__ ar,
                        const int* __restrict__ row_ptr, const int* __restrict__ col,
                        const float* __restrict__ W2, const float* __restrict__ b2,
                        const float* __restrict__ W3, const float* __restrict__ b3,
                        float* __restrict__ out_logits, float* __restrict__ out_encoded) {
    __shared__ uint32 sh_off[4][CAP + 4];
    __shared__ float4 sh_s4[4][CAP + 4];
    int lane = threadIdx.x & 63;
    int wid  = threadIdx.x >> 6;
    int n = blockIdx.x * 4 + wid;
    if (n >= N_NODES) return;

    int base = row_ptr[n];
    int deg  = row_ptr[n + 1] - base;

    float4 sdn = s1p[n];
    float sdv[HEADS] = {sdn.x, sdn.y, sdn.z, sdn.w};
    float alk[HEADS], ck[HEADS], alkB[HEADS], ckA[HEADS], ckB[HEADS], den[HEADS], num[HEADS];
    #pragma unroll
    for (int hd = 0; hd < HEADS; hd++) {
        alk[hd] = al[(hd * CONVS + 1) * 64 + lane] * LOG2E;
        ck[hd]  = ar[(hd * CONVS + 1) * 64 + lane] * LOG2E * sdv[hd];
    }

    float smx[HEADS] = {-INFINITY, -INFINITY, -INFINITY, -INFINITY};
    float smn[HEADS] = { INFINITY,  INFINITY,  INFINITY,  INFINITY};
    auto finalize = [&]() {
        #pragma unroll
        for (int hd = 0; hd < HEADS; hd++) {
            #pragma unroll
            for (int off = 32; off; off >>= 1) {
                smx[hd] = fmaxf(smx[hd], __shfl_xor(smx[hd], off));
                smn[hd] = fminf(smn[hd], __shfl_xor(smn[hd], off));
            }
            float t1 = fmaf(alk[hd], smx[hd], ck[hd]); t1 = fmaxf(t1, SLOPE * t1);
            float t2 = fmaf(alk[hd], smn[hd], ck[hd]); t2 = fmaxf(t2, SLOPE * t2);
            float mm = fmaxf(t1, t2);
            alkB[hd] = SLOPE * alk[hd];
            ckA[hd]  = ck[hd] - mm;
            ckB[hd]  = SLOPE * ck[hd] - mm;
            den[hd] = 0.f; num[hd] = 0.f;
        }
    };

    bool big = deg > CAP;
    if (big) {
        for (int j = lane; j < deg; j += 64) {
            float4 v = s1p[col[base + j]];
            float vv[HEADS] = {v.x, v.y, v.z, v.w};
            #pragma unroll
            for (int hd = 0; hd < HEADS; hd++) {
                smx[hd] = fmaxf(smx[hd], vv[hd]);
                smn[hd] = fminf(smn[hd], vv[hd]);
            }
        }
        finalize();
    }

#define C1C(S4, XV)                                                                \
    {                                                                              \
        float xf0 = bf_lo((XV).x), xf1 = bf_hi((XV).x);                            \
        float xf2 = bf_lo((XV).y), xf3 = bf_hi((XV).y);                            \
        float w0 = exp2f(fmaxf(fmaf(alk[0], (S4).x, ckA[0]), fmaf(alkB[0], (S4).x, ckB[0]))); \
        float w1 = exp2f(fmaxf(fmaf(alk[1], (S4).y, ckA[1]), fmaf(alkB[1], (S4).y, ckB[1]))); \
        float w2v = exp2f(fmaxf(fmaf(alk[2], (S4).z, ckA[2]), fmaf(alkB[2], (S4).z, ckB[2]))); \
        float w3 = exp2f(fmaxf(fmaf(alk[3], (S4).w, ckA[3]), fmaf(alkB[3], (S4).w, ckB[3]))); \
        den[0] += w0; den[1] += w1; den[2] += w2v; den[3] += w3;                   \
        num[0] = fmaf(xf0, w0, num[0]); num[1] = fmaf(xf1, w1, num[1]);            \
        num[2] = fmaf(xf2, w2v, num[2]); num[3] = fmaf(xf3, w3, num[3]);           \
    }

    uint32* offw = sh_off[wid];
    float4* s4w  = sh_s4[wid];
    const char* xb = (const char*)x1p + (size_t)lane * 8;   // 8B/lane, row = 512B
    int done = 0;
    while (done < deg) {
        int CH = min(deg - done, CAP);
        for (int j = lane; j < CH; j += 64) {
            int c = col[base + done + j];
            float4 v = s1p[c];
            offw[j] = (uint32)c << 9;
            s4w[j]  = v;
            if (!big) {
                float vv[HEADS] = {v.x, v.y, v.z, v.w};
                #pragma unroll
                for (int hd = 0; hd < HEADS; hd++) {
                    smx[hd] = fmaxf(smx[hd], vv[hd]);
                    smn[hd] = fminf(smn[hd], vv[hd]);
                }
            }
        }
        uint32 o0 = offw[0];
        if (lane < 4) offw[CH + lane] = o0;
        if (!big) finalize();

        uint2 x0, x1v, x2, x3;
        { uint32 o = offw[0]; x0  = *(const uint2*)(xb + o); }
        { uint32 o = offw[1]; x1v = *(const uint2*)(xb + o); }
        { uint32 o = offw[2]; x2  = *(const uint2*)(xb + o); }
        { uint32 o = offw[3]; x3  = *(const uint2*)(xb + o); }

        int ch4 = CH & ~3;
        for (int j = 0; j < ch4; j += 4) {
            { float4 s = s4w[j+0]; C1C(s, x0); }  { uint32 o = offw[j+4]; x0  = *(const uint2*)(xb + o); }
            { float4 s = s4w[j+1]; C1C(s, x1v); } { uint32 o = offw[j+5]; x1v = *(const uint2*)(xb + o); }
            { float4 s = s4w[j+2]; C1C(s, x2); }  { uint32 o = offw[j+6]; x2  = *(const uint2*)(xb + o); }
            { float4 s = s4w[j+3]; C1C(s, x3); }  { uint32 o = offw[j+7]; x3  = *(const uint2*)(xb + o); }
        }
        int rem = CH - ch4;
        if (rem > 0) { float4 s = s4w[ch4+0]; C1C(s, x0); }
        if (rem > 1) { float4 s = s4w[ch4+1]; C1C(s, x1v); }
        if (rem > 2) { float4 s = s4w[ch4+2]; C1C(s, x2); }
        done += CH;
    }
#undef C1C

    float hres = h[(size_t)n * 64 + lane];
    float z0 = fmaxf(hres + num[0] / den[0], 0.f);
    float z1 = fmaxf(hres + num[1] / den[1], 0.f);
    float z2 = fmaxf(hres + num[2] / den[2], 0.f);
    float z3 = fmaxf(hres + num[3] / den[3], 0.f);

    // encoded[n, lane] = sum_kk z[kk] * W2[kk, lane] + b2[lane]
    float acc = b2[lane];
    const float* w2p = W2 + lane;
    #pragma unroll 4
    for (int q = 0; q < 64; q++) { float zv = __shfl(z0, q); acc = fmaf(zv, w2p[(0 * 64 + q) * 64], acc); }
    #pragma unroll 4
    for (int q = 0; q < 64; q++) { float zv = __shfl(z1, q); acc = fmaf(zv, w2p[(1 * 64 + q) * 64], acc); }
    #pragma unroll 4
    for (int q = 0; q < 64; q++) { float zv = __shfl(z2, q); acc = fmaf(zv, w2p[(2 * 64 + q) * 64], acc); }
    #pragma unroll 4
    for (int q = 0; q < 64; q++) { float zv = __shfl(z3, q); acc = fmaf(zv, w2p[(3 * 64 + q) * 64], acc); }
    out_encoded[(size_t)n * 64 + lane] = acc;

    // logits[n, c] = sum_k relu(enc_k) * W3[k, c] + b3[c]
    float er = fmaxf(acc, 0.f);
    int c16 = lane & 15;
    int k0  = (lane >> 4) * 16;
    float part = 0.f;
    #pragma unroll
    for (int j = 0; j < 16; j++) {
        float ev = __shfl(er, k0 + j);
        part = fmaf(ev, W3[(k0 + j) * CLS + c16], part);
    }
    part += __shfl_xor(part, 16);
    part += __shfl_xor(part, 32);
    if (lane < CLS) out_logits[(size_t)n * CLS + lane] = part + b3[lane];
}

// ---------------- launch ----------------

extern "C" void kernel_launch(void* const* d_in, const int* in_sizes, int n_in,
                              void* d_out, int out_size, void* d_ws, size_t ws_size,
                              hipStream_t stream) {
    const float* feat0 = (const float*)d_in[0];
    const float* feat1 = (const float*)d_in[1];
    const float* feat2 = (const float*)d_in[2];
    const int*   src   = (const int*)d_in[3];
    const int*   dst   = (const int*)d_in[4];
    const float* W1_0  = (const float*)d_in[5];
    const float* b1_0  = (const float*)d_in[6];
    const float* W1_1  = (const float*)d_in[7];
    const float* b1_1  = (const float*)d_in[8];
    const float* W1_2  = (const float*)d_in[9];
    const float* b1_2  = (const float*)d_in[10];
    const float* al    = (const float*)d_in[11];
    const float* ar    = (const float*)d_in[12];
    const float* W2    = (const float*)d_in[13];
    const float* b2    = (const float*)d_in[14];
    const float* W3    = (const float*)d_in[15];
    const float* b3    = (const float*)d_in[16];

    float* out_logits  = (float*)d_out;
    float* out_encoded = (float*)d_out + (size_t)N_NODES * CLS;

    char* ws = (char*)d_ws;
    size_t off = 0;
    auto alloc = [&](size_t bytes) {
        void* p = ws + off;
        off = (off + bytes + 255) & ~(size_t)255;
        return p;
    };
    int*      row_ptr = (int*)alloc((N_NODES + 1) * sizeof(int));
    int*      deg     = (int*)alloc(N_NODES * sizeof(int));
    int*      tops    = (int*)alloc(64 * sizeof(int));
    int*      col     = (int*)alloc((size_t)N_EDGES * sizeof(int));
    float*    h       = (float*)alloc((size_t)N_NODES * 64 * sizeof(float));
    ushort16* hb      = (ushort16*)alloc((size_t)N_NODES * 64 * sizeof(ushort16));
    float*    s_h     = (float*)alloc(N_NODES * sizeof(float));
    ushort16* x1p     = (ushort16*)alloc((size_t)N_NODES * 64 * 4 * sizeof(ushort16));
    float4*   s1p     = (float4*)alloc(N_NODES * sizeof(float4));
    (void)ws_size; (void)in_sizes; (void)n_in; (void)out_size;

    // CSR by dst
    (void)hipMemsetAsync(deg, 0, N_NODES * sizeof(int), stream);
    hist_kernel<<<(N_EDGES + 255) / 256, 256, 0, stream>>>(dst, deg);
    int nb = (N_NODES + SCAN_B - 1) / SCAN_B;
    scan1_kernel<<<nb, SCAN_B, 0, stream>>>(deg, row_ptr, tops);
    scan2_kernel<<<1, 64, 0, stream>>>(tops, nb);
    scan3_kernel<<<nb, SCAN_B, 0, stream>>>(row_ptr, tops);
    (void)hipMemsetAsync(deg, 0, N_NODES * sizeof(int), stream);
    scatter_kernel<<<(N_EDGES + 255) / 256, 256, 0, stream>>>(src, dst, row_ptr, deg, col);

    // projections
    proj_kernel<<<(20000 + 3) / 4, 256, 0, stream>>>(feat0, W1_0, b1_0, h, hb, s_h, 20000, 256, 0);
    proj_kernel<<<(15000 + 3) / 4, 256, 0, stream>>>(feat1, W1_1, b1_1, h, hb, s_h, 15000, 128, 20000);
    proj_kernel<<<(15000 + 3) / 4, 256, 0, stream>>>(feat2, W1_2, b1_2, h, hb, s_h, 15000, 64, 35000);

    // convs + epilogue
    conv0_kernel<<<(N_NODES + 3) / 4, 256, 0, stream>>>(hb, s_h, al, ar, row_ptr, col, x1p, s1p);
    conv1_fused_kernel<<<(N_NODES + 3) / 4, 256, 0, stream>>>(h, x1p, s1p, al, ar, row_ptr, col,
                                                              W2, b2, W3, b3,
                                                              out_logits, out_encoded);
}

// Round 6
// 493.772 us; speedup vs baseline: 1.1533x; 1.1533x over previous
//
#include <hip/hip_runtime.h>
#include <hip/hip_bf16.h>
#include <hip/hip_fp16.h>
#include <cmath>

#define N_NODES 50000
#define N_EDGES 800000
#define HID 64
#define HEADS 4
#define CONVS 2
#define CLS 16
#define SLOPE 0.2f
#define SCAN_B 1024
#define LOG2E 1.4426950408889634f

typedef unsigned int  uint32;
typedef unsigned short ushort16;

__device__ __forceinline__ ushort16 f2bf(float x) {
    union { float f; uint32 u; } v; v.f = x;
    uint32 r = v.u + 0x7fffu + ((v.u >> 16) & 1u);   // RNE
    return (ushort16)(r >> 16);
}
__device__ __forceinline__ float bf_lo(uint32 w) { return __uint_as_float(w << 16); }
__device__ __forceinline__ float bf_hi(uint32 w) { return __uint_as_float(w & 0xffff0000u); }

// ---------------- CSR build ----------------

__global__ void hist_kernel(const int* __restrict__ dst, int* __restrict__ deg) {
    int e = blockIdx.x * blockDim.x + threadIdx.x;
    if (e < N_EDGES) atomicAdd(&deg[dst[e]], 1);
}

__global__ void scan1_kernel(const int* __restrict__ deg, int* __restrict__ row_ptr,
                             int* __restrict__ tops) {
    __shared__ int buf[SCAN_B];
    int i = blockIdx.x * SCAN_B + threadIdx.x;
    int v = (i < N_NODES) ? deg[i] : 0;
    buf[threadIdx.x] = v;
    __syncthreads();
    for (int off = 1; off < SCAN_B; off <<= 1) {
        int t = (threadIdx.x >= off) ? buf[threadIdx.x - off] : 0;
        __syncthreads();
        buf[threadIdx.x] += t;
        __syncthreads();
    }
    if (i < N_NODES) row_ptr[i + 1] = buf[threadIdx.x];
    if (threadIdx.x == SCAN_B - 1) tops[blockIdx.x] = buf[threadIdx.x];
}

__global__ void scan2_kernel(int* __restrict__ tops, int nb) {
    if (threadIdx.x == 0 && blockIdx.x == 0) {
        int acc = 0;
        for (int b = 0; b < nb; b++) { int t = tops[b]; tops[b] = acc; acc += t; }
    }
}

__global__ void scan3_kernel(int* __restrict__ row_ptr, const int* __restrict__ tops) {
    int i = blockIdx.x * SCAN_B + threadIdx.x;
    if (i < N_NODES) row_ptr[i + 1] += tops[blockIdx.x];
    if (i == 0 && blockIdx.x == 0) row_ptr[0] = 0;
}

__global__ void scatter_kernel(const int* __restrict__ src, const int* __restrict__ dst,
                               const int* __restrict__ row_ptr, int* __restrict__ cursor,
                               int* __restrict__ col) {
    int e = blockIdx.x * blockDim.x + threadIdx.x;
    if (e < N_EDGES) {
        int d = dst[e];
        int pos = row_ptr[d] + atomicAdd(&cursor[d], 1);
        col[pos] = src[e];
    }
}

// ---------------- per-type projection: h = feat @ W1 + b1 (+ bf16 copy, rowsum) --------

__global__ __launch_bounds__(256)
void proj_kernel(const float* __restrict__ feat, const float* __restrict__ W,
                 const float* __restrict__ b, float* __restrict__ h,
                 ushort16* __restrict__ hb, float* __restrict__ s_out,
                 int rows, int K, int base_row) {
    int lane = threadIdx.x & 63;
    int wid  = threadIdx.x >> 6;
    int r = blockIdx.x * 4 + wid;
    if (r >= rows) return;
    const float* arow = feat + (size_t)r * K;
    float acc = b[lane];
    for (int kk = 0; kk < K; kk += 4) {
        float4 a4 = *reinterpret_cast<const float4*>(arow + kk);
        acc = fmaf(a4.x, W[(kk + 0) * 64 + lane], acc);
        acc = fmaf(a4.y, W[(kk + 1) * 64 + lane], acc);
        acc = fmaf(a4.z, W[(kk + 2) * 64 + lane], acc);
        acc = fmaf(a4.w, W[(kk + 3) * 64 + lane], acc);
    }
    int gr = base_row + r;
    h[(size_t)gr * 64 + lane]  = acc;
    hb[(size_t)gr * 64 + lane] = f2bf(acc);
    float ssum = acc;
    #pragma unroll
    for (int off = 32; off; off >>= 1) ssum += __shfl_xor(ssum, off);
    if (lane == 0) s_out[gr] = ssum;
}

// ---------------- conv 0 (R3 structure: 1-deep prefetch, bf16 gather) ----------------

__global__ __launch_bounds__(256)
void conv0_kernel(const ushort16* __restrict__ hb, const float* __restrict__ s_h,
                  const float* __restrict__ al, const float* __restrict__ ar,
                  const int* __restrict__ row_ptr, const int* __restrict__ col,
                  ushort16* __restrict__ x1p, float4* __restrict__ s1p) {
    int lane = threadIdx.x & 63;
    int wid  = threadIdx.x >> 6;
    int n = blockIdx.x * 4 + wid;
    if (n >= N_NODES) return;

    float sd = s_h[n];
    int base = row_ptr[n];
    int deg  = row_ptr[n + 1] - base;

    float alk[HEADS], ck[HEADS], mm[HEADS], den[HEADS], num[HEADS];
    #pragma unroll
    for (int hd = 0; hd < HEADS; hd++) {
        alk[hd] = al[(hd * CONVS + 0) * 64 + lane] * LOG2E;
        ck[hd]  = ar[(hd * CONVS + 0) * 64 + lane] * LOG2E * sd;
    }

    float smax = -INFINITY, smin = INFINITY;
    for (int j = lane; j < deg; j += 64) {
        float sv = s_h[col[base + j]];
        smax = fmaxf(smax, sv);
        smin = fminf(smin, sv);
    }
    #pragma unroll
    for (int off = 32; off; off >>= 1) {
        smax = fmaxf(smax, __shfl_xor(smax, off));
        smin = fminf(smin, __shfl_xor(smin, off));
    }
    #pragma unroll
    for (int hd = 0; hd < HEADS; hd++) {
        float t1 = fmaf(alk[hd], smax, ck[hd]); t1 = fmaxf(t1, SLOPE * t1);
        float t2 = fmaf(alk[hd], smin, ck[hd]); t2 = fmaxf(t2, SLOPE * t2);
        mm[hd] = fmaxf(t1, t2);
        den[hd] = 0.f; num[hd] = 0.f;
    }

    // 1-deep prefetch main loop
    int cj = col[base];
    float sv = s_h[cj];
    ushort16 hv = hb[(size_t)cj * 64 + lane];
    for (int j = 0; j < deg; j++) {
        int jn = (j + 1 < deg) ? j + 1 : j;
        int cn = col[base + jn];
        float sn = s_h[cn];
        ushort16 hn = hb[(size_t)cn * 64 + lane];
        float hf = __uint_as_float(((uint32)hv) << 16);
        #pragma unroll
        for (int hd = 0; hd < HEADS; hd++) {
            float t = fmaf(alk[hd], sv, ck[hd]);
            t = fmaxf(t, SLOPE * t);
            float w = exp2f(t - mm[hd]);
            den[hd] += w;
            num[hd] = fmaf(hf, w, num[hd]);
        }
        sv = sn; hv = hn;
    }

    float o[HEADS];
    #pragma unroll
    for (int hd = 0; hd < HEADS; hd++) o[hd] = num[hd] / den[hd];

    uint32 lo = ((uint32)f2bf(o[0])) | (((uint32)f2bf(o[1])) << 16);
    uint32 hi = ((uint32)f2bf(o[2])) | (((uint32)f2bf(o[3])) << 16);
    *reinterpret_cast<uint2*>(x1p + ((size_t)n * 64 + lane) * 4) = make_uint2(lo, hi);

    float s0 = o[0], s1v = o[1], s2 = o[2], s3 = o[3];
    #pragma unroll
    for (int off = 32; off; off >>= 1) {
        s0 += __shfl_xor(s0, off); s1v += __shfl_xor(s1v, off);
        s2 += __shfl_xor(s2, off); s3  += __shfl_xor(s3, off);
    }
    if (lane == 0) s1p[n] = make_float4(s0, s1v, s2, s3);
}

// ------- conv 1 (R3 structure) + residual + relu; writes packed fp16 z -------

__global__ __launch_bounds__(256)
void conv1_kernel(const float* __restrict__ h, const ushort16* __restrict__ x1p,
                  const float4* __restrict__ s1p,
                  const float* __restrict__ al, const float* __restrict__ ar,
                  const int* __restrict__ row_ptr, const int* __restrict__ col,
                  uint2* __restrict__ zh /* [N][64 lanes][4 heads] fp16 */) {
    int lane = threadIdx.x & 63;
    int wid  = threadIdx.x >> 6;
    int n = blockIdx.x * 4 + wid;
    if (n >= N_NODES) return;

    int base = row_ptr[n];
    int deg  = row_ptr[n + 1] - base;

    float4 sdn = s1p[n];
    float sdv[HEADS] = {sdn.x, sdn.y, sdn.z, sdn.w};
    float alk[HEADS], ck[HEADS], mm[HEADS], den[HEADS], num[HEADS];
    #pragma unroll
    for (int hd = 0; hd < HEADS; hd++) {
        alk[hd] = al[(hd * CONVS + 1) * 64 + lane] * LOG2E;
        ck[hd]  = ar[(hd * CONVS + 1) * 64 + lane] * LOG2E * sdv[hd];
    }

    float smax0 = -INFINITY, smin0 = INFINITY, smax1 = -INFINITY, smin1 = INFINITY;
    float smax2 = -INFINITY, smin2 = INFINITY, smax3 = -INFINITY, smin3 = INFINITY;
    for (int j = lane; j < deg; j += 64) {
        float4 v = s1p[col[base + j]];
        smax0 = fmaxf(smax0, v.x); smin0 = fminf(smin0, v.x);
        smax1 = fmaxf(smax1, v.y); smin1 = fminf(smin1, v.y);
        smax2 = fmaxf(smax2, v.z); smin2 = fminf(smin2, v.z);
        smax3 = fmaxf(smax3, v.w); smin3 = fminf(smin3, v.w);
    }
    #pragma unroll
    for (int off = 32; off; off >>= 1) {
        smax0 = fmaxf(smax0, __shfl_xor(smax0, off)); smin0 = fminf(smin0, __shfl_xor(smin0, off));
        smax1 = fmaxf(smax1, __shfl_xor(smax1, off)); smin1 = fminf(smin1, __shfl_xor(smin1, off));
        smax2 = fmaxf(smax2, __shfl_xor(smax2, off)); smin2 = fminf(smin2, __shfl_xor(smin2, off));
        smax3 = fmaxf(smax3, __shfl_xor(smax3, off)); smin3 = fminf(smin3, __shfl_xor(smin3, off));
    }
    {
        float smaxA[HEADS] = {smax0, smax1, smax2, smax3};
        float sminA[HEADS] = {smin0, smin1, smin2, smin3};
        #pragma unroll
        for (int hd = 0; hd < HEADS; hd++) {
            float t1 = fmaf(alk[hd], smaxA[hd], ck[hd]); t1 = fmaxf(t1, SLOPE * t1);
            float t2 = fmaf(alk[hd], sminA[hd], ck[hd]); t2 = fmaxf(t2, SLOPE * t2);
            mm[hd] = fmaxf(t1, t2);
            den[hd] = 0.f; num[hd] = 0.f;
        }
    }

    // main loop: per edge 3 loads (col, s1p float4 broadcast, x1p 8B gather), 1-deep prefetch
    int cj = col[base];
    float4 sv4 = s1p[cj];
    uint2 xv = *reinterpret_cast<const uint2*>(x1p + ((size_t)cj * 64 + lane) * 4);
    for (int j = 0; j < deg; j++) {
        int jn = (j + 1 < deg) ? j + 1 : j;
        int cn = col[base + jn];
        float4 sn4 = s1p[cn];
        uint2 xn = *reinterpret_cast<const uint2*>(x1p + ((size_t)cn * 64 + lane) * 4);
        float xf[HEADS] = {bf_lo(xv.x), bf_hi(xv.x), bf_lo(xv.y), bf_hi(xv.y)};
        float sf[HEADS] = {sv4.x, sv4.y, sv4.z, sv4.w};
        #pragma unroll
        for (int hd = 0; hd < HEADS; hd++) {
            float t = fmaf(alk[hd], sf[hd], ck[hd]);
            t = fmaxf(t, SLOPE * t);
            float w = exp2f(t - mm[hd]);
            den[hd] += w;
            num[hd] = fmaf(xf[hd], w, num[hd]);
        }
        sv4 = sn4; xv = xn;
    }

    float hres = h[(size_t)n * 64 + lane];
    float z0 = fmaxf(hres + num[0] / den[0], 0.f);
    float z1 = fmaxf(hres + num[1] / den[1], 0.f);
    float z2 = fmaxf(hres + num[2] / den[2], 0.f);
    float z3 = fmaxf(hres + num[3] / den[3], 0.f);

    __half2 p01 = __floats2half2_rn(z0, z1);
    __half2 p23 = __floats2half2_rn(z2, z3);
    uint2 pk;
    pk.x = *reinterpret_cast<uint32*>(&p01);
    pk.y = *reinterpret_cast<uint32*>(&p23);
    zh[(size_t)n * 64 + lane] = pk;   // coalesced 512B per wave
}

// ------- W2 reorder to match z packing: W2r[(q*4+hd)*64+col] = W2[(hd*64+q)*64+col] ----

__global__ void w2r_kernel(const float* __restrict__ W2, float* __restrict__ W2r) {
    int col = threadIdx.x;         // 64
    int idx = blockIdx.x;          // 256 = q*4+hd
    int q = idx >> 2, hd = idx & 3;
    W2r[idx * 64 + col] = W2[(hd * 64 + q) * 64 + col];
}

// ------- encoded = z @ W2 + b2 (streaming GEMM, no shuffles; 4 rows/wave) -------

__global__ __launch_bounds__(256)
void zgemm_kernel(const uint2* __restrict__ zh, const float* __restrict__ W2r,
                  const float* __restrict__ b2, float* __restrict__ out_encoded) {
    int lane = threadIdx.x & 63;
    int wid  = threadIdx.x >> 6;
    int r0 = (blockIdx.x * 4 + wid) * 4;      // 4 rows per wave
    if (r0 >= N_NODES) return;

    float bb = b2[lane];
    float a0 = bb, a1 = bb, a2 = bb, a3 = bb;
    const uint2* z0 = zh + (size_t)r0 * 64;

    for (int q = 0; q < 64; q += 2) {
        float w[8];
        const float* wp = W2r + (q * 4) * 64 + lane;
        #pragma unroll
        for (int t = 0; t < 8; t++) w[t] = wp[t * 64];

        #pragma unroll
        for (int rr = 0; rr < 4; rr++) {
            uint4 zz = *reinterpret_cast<const uint4*>(z0 + rr * 64 + q);
            float2 fA = __half22float2(*reinterpret_cast<const __half2*>(&zz.x)); // (q,hd0),(q,hd1)
            float2 fB = __half22float2(*reinterpret_cast<const __half2*>(&zz.y)); // (q,hd2),(q,hd3)
            float2 fC = __half22float2(*reinterpret_cast<const __half2*>(&zz.z)); // (q+1,hd0..1)
            float2 fD = __half22float2(*reinterpret_cast<const __half2*>(&zz.w)); // (q+1,hd2..3)
            float acc = (rr == 0) ? a0 : (rr == 1) ? a1 : (rr == 2) ? a2 : a3;
            acc = fmaf(fA.x, w[0], acc);
            acc = fmaf(fA.y, w[1], acc);
            acc = fmaf(fB.x, w[2], acc);
            acc = fmaf(fB.y, w[3], acc);
            acc = fmaf(fC.x, w[4], acc);
            acc = fmaf(fC.y, w[5], acc);
            acc = fmaf(fD.x, w[6], acc);
            acc = fmaf(fD.y, w[7], acc);
            if (rr == 0) a0 = acc; else if (rr == 1) a1 = acc; else if (rr == 2) a2 = acc; else a3 = acc;
        }
    }
    out_encoded[(size_t)(r0 + 0) * 64 + lane] = a0;
    out_encoded[(size_t)(r0 + 1) * 64 + lane] = a1;
    out_encoded[(size_t)(r0 + 2) * 64 + lane] = a2;
    out_encoded[(size_t)(r0 + 3) * 64 + lane] = a3;
}

// ------- logits = relu(encoded) @ W3 + b3 -------

__global__ __launch_bounds__(256)
void logits_kernel(const float* __restrict__ enc, const float* __restrict__ W3,
                   const float* __restrict__ b3, float* __restrict__ out_logits) {
    int t = blockIdx.x * 256 + threadIdx.x;
    int r = t >> 4, c = t & 15;
    if (r >= N_NODES) return;
    float acc = b3[c];
    const float* er = enc + (size_t)r * 64;
    #pragma unroll 8
    for (int k = 0; k < 64; k++)
        acc = fmaf(fmaxf(er[k], 0.f), W3[k * CLS + c], acc);
    out_logits[(size_t)r * CLS + c] = acc;
}

// ---------------- launch ----------------

extern "C" void kernel_launch(void* const* d_in, const int* in_sizes, int n_in,
                              void* d_out, int out_size, void* d_ws, size_t ws_size,
                              hipStream_t stream) {
    const float* feat0 = (const float*)d_in[0];
    const float* feat1 = (const float*)d_in[1];
    const float* feat2 = (const float*)d_in[2];
    const int*   src   = (const int*)d_in[3];
    const int*   dst   = (const int*)d_in[4];
    const float* W1_0  = (const float*)d_in[5];
    const float* b1_0  = (const float*)d_in[6];
    const float* W1_1  = (const float*)d_in[7];
    const float* b1_1  = (const float*)d_in[8];
    const float* W1_2  = (const float*)d_in[9];
    const float* b1_2  = (const float*)d_in[10];
    const float* al    = (const float*)d_in[11];
    const float* ar    = (const float*)d_in[12];
    const float* W2    = (const float*)d_in[13];
    const float* b2    = (const float*)d_in[14];
    const float* W3    = (const float*)d_in[15];
    const float* b3    = (const float*)d_in[16];

    float* out_logits  = (float*)d_out;
    float* out_encoded = (float*)d_out + (size_t)N_NODES * CLS;

    char* ws = (char*)d_ws;
    size_t off = 0;
    auto alloc = [&](size_t bytes) {
        void* p = ws + off;
        off = (off + bytes + 255) & ~(size_t)255;
        return p;
    };
    int*      row_ptr = (int*)alloc((N_NODES + 1) * sizeof(int));
    int*      deg     = (int*)alloc(N_NODES * sizeof(int));
    int*      tops    = (int*)alloc(64 * sizeof(int));
    int*      col     = (int*)alloc((size_t)N_EDGES * sizeof(int));
    float*    h       = (float*)alloc((size_t)N_NODES * 64 * sizeof(float));
    ushort16* hb      = (ushort16*)alloc((size_t)N_NODES * 64 * sizeof(ushort16));
    float*    s_h     = (float*)alloc(N_NODES * sizeof(float));
    ushort16* x1p     = (ushort16*)alloc((size_t)N_NODES * 64 * 4 * sizeof(ushort16));
    float4*   s1p     = (float4*)alloc(N_NODES * sizeof(float4));
    uint2*    zh      = (uint2*)alloc((size_t)N_NODES * 64 * sizeof(uint2));
    float*    W2r     = (float*)alloc(256 * 64 * sizeof(float));
    (void)ws_size; (void)in_sizes; (void)n_in; (void)out_size;

    // CSR by dst
    (void)hipMemsetAsync(deg, 0, N_NODES * sizeof(int), stream);
    hist_kernel<<<(N_EDGES + 255) / 256, 256, 0, stream>>>(dst, deg);
    int nb = (N_NODES + SCAN_B - 1) / SCAN_B;
    scan1_kernel<<<nb, SCAN_B, 0, stream>>>(deg, row_ptr, tops);
    scan2_kernel<<<1, 64, 0, stream>>>(tops, nb);
    scan3_kernel<<<nb, SCAN_B, 0, stream>>>(row_ptr, tops);
    (void)hipMemsetAsync(deg, 0, N_NODES * sizeof(int), stream);
    scatter_kernel<<<(N_EDGES + 255) / 256, 256, 0, stream>>>(src, dst, row_ptr, deg, col);

    // W2 reorder (independent; overlaps with CSR tail)
    w2r_kernel<<<256, 64, 0, stream>>>(W2, W2r);

    // projections
    proj_kernel<<<(20000 + 3) / 4, 256, 0, stream>>>(feat0, W1_0, b1_0, h, hb, s_h, 20000, 256, 0);
    proj_kernel<<<(15000 + 3) / 4, 256, 0, stream>>>(feat1, W1_1, b1_1, h, hb, s_h, 15000, 128, 20000);
    proj_kernel<<<(15000 + 3) / 4, 256, 0, stream>>>(feat2, W1_2, b1_2, h, hb, s_h, 15000, 64, 35000);

    // convs
    conv0_kernel<<<(N_NODES + 3) / 4, 256, 0, stream>>>(hb, s_h, al, ar, row_ptr, col, x1p, s1p);
    conv1_kernel<<<(N_NODES + 3) / 4, 256, 0, stream>>>(h, x1p, s1p, al, ar, row_ptr, col, zh);

    // epilogue GEMMs
    zgemm_kernel<<<(N_NODES / 16), 256, 0, stream>>>(zh, W2r, b2, out_encoded);
    logits_kernel<<<(N_NODES * CLS + 255) / 256, 256, 0, stream>>>(out_encoded, W3, b3, out_logits);
}